// Round 3
// baseline (119.609 us; speedup 1.0000x reference)
//
#include <hip/hip_runtime.h>

// YOLOX head decode, fused single-launch, TP=128 version.
// (N, A*85, H, W) -> (N, A*H*W, 85) with sigmoid on obj/cls and box decode
// on channels 0..3. Streaming transpose: coalesced float4 reads per
// channel-plane (512 B/plane/block) -> LDS [pos][85] -> coalesced float4
// writes of the contiguous output region. One launch, biggest level first.
// Nontemporal on both sides (touch-once data).

typedef float v4f __attribute__((ext_vector_type(4)));

#define NATT 85
#define TP 128             // positions per block (512 B read segment/plane)
#define TOTAL_ROWS 25200

__device__ __forceinline__ float sigmf(float v) {
    return 1.0f / (1.0f + __expf(-v));
}

template <int LVL>
__device__ __forceinline__ void process(const float* __restrict__ in,
                                        float* __restrict__ out,
                                        int id, float* lds) {
    constexpr int   H  = (LVL == 0) ? 20 : (LVL == 1) ? 40 : 80;
    constexpr int   W  = H;
    constexpr int   HW = H * W;
    constexpr float S  = (LVL == 0) ? 32.f : (LVL == 1) ? 16.f : 8.f;
    constexpr int   OUT_BASE = (LVL == 0) ? 0 : (LVL == 1) ? 1200 : 6000;
    constexpr int   C  = (HW + TP - 1) / TP;   // chunks per (n,a): 4 / 13 / 50

    const int tid   = threadIdx.x;     // 256 threads = 4 waves
    const int chunk = id % C;
    const int ta    = id / C;
    const int a     = ta % 3;          // anchor
    const int n     = ta / 3;          // batch

    const int pos0  = chunk * TP;
    const int valid = (HW - pos0 < TP) ? (HW - pos0) : TP;  // 128 / 64 / 16

    // input plane base for (n, anchor a, k=0) at this position chunk
    const float* inp = in + ((size_t)n * 255 + (size_t)a * NATT) * HW + pos0;

    // ---- load phase: 16 lanes per plane, 2x float4 along positions ----
    const int m = tid & 15;        // which float4 within each 64-pos half
    const int p = m * 4;           // position offset of this vec
    for (int kk = tid >> 4; kk < NATT; kk += 16) {
        const float* plane = inp + (size_t)kk * HW;
        if (p < valid) {
            v4f v = __builtin_nontemporal_load(
                reinterpret_cast<const v4f*>(plane + p));
            if (kk >= 4) {
                v.x = sigmf(v.x); v.y = sigmf(v.y);
                v.z = sigmf(v.z); v.w = sigmf(v.w);
            }
            lds[(p + 0) * NATT + kk] = v.x;
            lds[(p + 1) * NATT + kk] = v.y;
            lds[(p + 2) * NATT + kk] = v.z;
            lds[(p + 3) * NATT + kk] = v.w;
        }
        if (p + 64 < valid) {
            v4f v = __builtin_nontemporal_load(
                reinterpret_cast<const v4f*>(plane + p + 64));
            if (kk >= 4) {
                v.x = sigmf(v.x); v.y = sigmf(v.y);
                v.z = sigmf(v.z); v.w = sigmf(v.w);
            }
            lds[(p + 64) * NATT + kk] = v.x;
            lds[(p + 65) * NATT + kk] = v.y;
            lds[(p + 66) * NATT + kk] = v.z;
            lds[(p + 67) * NATT + kk] = v.w;
        }
    }
    __syncthreads();

    // ---- fix-up phase: decode boxes in place (one lane per position) ----
    if (tid < valid) {             // valid <= 128 <= blockDim
        const int gp = pos0 + tid;
        const int y  = gp / W;
        const int x  = gp - y * W;
        const float wa = (a == 0) ? ((LVL == 0) ? 116.f : (LVL == 1) ? 30.f : 10.f)
                       : (a == 1) ? ((LVL == 0) ? 156.f : (LVL == 1) ? 62.f : 16.f)
                                  : ((LVL == 0) ? 373.f : (LVL == 1) ? 59.f : 33.f);
        const float ha = (a == 0) ? ((LVL == 0) ?  90.f : (LVL == 1) ? 61.f : 13.f)
                       : (a == 1) ? ((LVL == 0) ? 198.f : (LVL == 1) ? 45.f : 30.f)
                                  : ((LVL == 0) ? 326.f : (LVL == 1) ? 119.f : 23.f);
        const float p0 = lds[tid * NATT + 0];
        const float p1 = lds[tid * NATT + 1];
        const float p2 = lds[tid * NATT + 2];
        const float p3 = lds[tid * NATT + 3];
        // (p0-0.5)*S + (x+0.5)*S == (p0+x)*S
        const float xc = (p0 + (float)x) * S;
        const float yc = (p1 + (float)y) * S;
        const float w  = __expf(p2) * wa;
        const float h  = __expf(p3) * ha;
        lds[tid * NATT + 0] = xc - 0.5f * w;
        lds[tid * NATT + 1] = yc - 0.5f * h;
        lds[tid * NATT + 2] = xc + 0.5f * w;
        lds[tid * NATT + 3] = yc + 0.5f * h;
    }
    __syncthreads();

    // ---- write phase: output region is valid*85 contiguous floats ----
    const size_t row0 = (size_t)n * TOTAL_ROWS + OUT_BASE + (size_t)a * HW + pos0;
    float* op = out + row0 * NATT;
    const int nfl = valid * NATT;          // up to 10880, divisible by 4
    for (int i = tid * 4; i + 3 < nfl; i += 1024) {
        __builtin_nontemporal_store(*reinterpret_cast<const v4f*>(lds + i),
                                    reinterpret_cast<v4f*>(op + i));
    }
}

// Block counts: lvl2 = 50*3*32 = 4800, lvl1 = 13*3*32 = 1248,
// lvl0 = 4*3*32 = 384. Total 6432. Biggest level first.
__global__ __launch_bounds__(256) void yolox_fused(const float* __restrict__ in0,
                                                   const float* __restrict__ in1,
                                                   const float* __restrict__ in2,
                                                   float* __restrict__ out) {
    __shared__ float lds[TP * NATT];   // 43520 B, shared by all paths
    const int bid = blockIdx.x;
    if (bid < 4800) {
        process<2>(in2, out, bid, lds);
    } else if (bid < 6048) {
        process<1>(in1, out, bid - 4800, lds);
    } else {
        process<0>(in0, out, bid - 6048, lds);
    }
}

extern "C" void kernel_launch(void* const* d_in, const int* in_sizes, int n_in,
                              void* d_out, int out_size, void* d_ws, size_t ws_size,
                              hipStream_t stream) {
    const float* in0 = (const float*)d_in[0];  // (32,255,20,20)
    const float* in1 = (const float*)d_in[1];  // (32,255,40,40)
    const float* in2 = (const float*)d_in[2];  // (32,255,80,80)
    float* out = (float*)d_out;                // (32,25200,85)

    yolox_fused<<<dim3(6432), dim3(256), 0, stream>>>(in0, in1, in2, out);
}

// Round 4
// 95.612 us; speedup vs baseline: 1.2510x; 1.2510x over previous
//
#include <hip/hip_runtime.h>

// YOLOX head decode, fused single-launch, TP=64 (R2 structure).
// (N, A*85, H, W) -> (N, A*H*W, 85) with sigmoid on obj/cls and box decode
// on channels 0..3. Streaming transpose: coalesced float4 reads per
// channel-plane -> LDS [pos][85] -> coalesced float4 writes of the
// contiguous output region.
//
// Cache policy experiment: loads are PLAIN (allocate in the 256 MiB
// memory-side Infinity Cache -- the 254 MB input set fits and is re-read
// on every graph replay), stores are NONTEMPORAL (output is never read by
// us; keep the writes from evicting the L3-resident inputs).

typedef float v4f __attribute__((ext_vector_type(4)));

#define NATT 85
#define TP 64              // positions per block
#define TOTAL_ROWS 25200

__device__ __forceinline__ float sigmf(float v) {
    return 1.0f / (1.0f + __expf(-v));
}

template <int LVL>
__device__ __forceinline__ void process(const float* __restrict__ in,
                                        float* __restrict__ out,
                                        int id, float* lds) {
    constexpr int   H  = (LVL == 0) ? 20 : (LVL == 1) ? 40 : 80;
    constexpr int   W  = H;
    constexpr int   HW = H * W;
    constexpr float S  = (LVL == 0) ? 32.f : (LVL == 1) ? 16.f : 8.f;
    constexpr int   OUT_BASE = (LVL == 0) ? 0 : (LVL == 1) ? 1200 : 6000;
    constexpr int   C  = (HW + TP - 1) / TP;   // chunks per (n,a): 7 / 25 / 100

    const int tid   = threadIdx.x;     // 256 threads = 4 waves
    const int chunk = id % C;
    const int ta    = id / C;
    const int a     = ta % 3;          // anchor
    const int n     = ta / 3;          // batch

    const int pos0  = chunk * TP;
    const int valid = (HW - pos0 < TP) ? (HW - pos0) : TP;  // 64, or 16 (lvl0 tail)

    // input plane base for (n, anchor a, k=0) at this position chunk
    const float* inp = in + ((size_t)n * 255 + (size_t)a * NATT) * HW + pos0;

    // ---- load phase: 16 lanes per plane, float4 along positions ----
    const int m = tid & 15;        // which float4 within the 64-pos chunk
    const int p = m * 4;           // position offset of this vec
    for (int kk = tid >> 4; kk < NATT; kk += 16) {
        if (p < valid) {           // valid is always a multiple of 4
            v4f v = *reinterpret_cast<const v4f*>(inp + (size_t)kk * HW + p);
            if (kk >= 4) {
                v.x = sigmf(v.x); v.y = sigmf(v.y);
                v.z = sigmf(v.z); v.w = sigmf(v.w);
            }
            lds[(p + 0) * NATT + kk] = v.x;
            lds[(p + 1) * NATT + kk] = v.y;
            lds[(p + 2) * NATT + kk] = v.z;
            lds[(p + 3) * NATT + kk] = v.w;
        }
    }
    __syncthreads();

    // ---- fix-up phase: decode boxes in place (one lane per position) ----
    if (tid < TP && tid < valid) {
        const int gp = pos0 + tid;
        const int y  = gp / W;
        const int x  = gp - y * W;
        const float wa = (a == 0) ? ((LVL == 0) ? 116.f : (LVL == 1) ? 30.f : 10.f)
                       : (a == 1) ? ((LVL == 0) ? 156.f : (LVL == 1) ? 62.f : 16.f)
                                  : ((LVL == 0) ? 373.f : (LVL == 1) ? 59.f : 33.f);
        const float ha = (a == 0) ? ((LVL == 0) ?  90.f : (LVL == 1) ? 61.f : 13.f)
                       : (a == 1) ? ((LVL == 0) ? 198.f : (LVL == 1) ? 45.f : 30.f)
                                  : ((LVL == 0) ? 326.f : (LVL == 1) ? 119.f : 23.f);
        const float p0 = lds[tid * NATT + 0];
        const float p1 = lds[tid * NATT + 1];
        const float p2 = lds[tid * NATT + 2];
        const float p3 = lds[tid * NATT + 3];
        // (p0-0.5)*S + (x+0.5)*S == (p0+x)*S
        const float xc = (p0 + (float)x) * S;
        const float yc = (p1 + (float)y) * S;
        const float w  = __expf(p2) * wa;
        const float h  = __expf(p3) * ha;
        lds[tid * NATT + 0] = xc - 0.5f * w;
        lds[tid * NATT + 1] = yc - 0.5f * h;
        lds[tid * NATT + 2] = xc + 0.5f * w;
        lds[tid * NATT + 3] = yc + 0.5f * h;
    }
    __syncthreads();

    // ---- write phase: output region is valid*85 contiguous floats ----
    const size_t row0 = (size_t)n * TOTAL_ROWS + OUT_BASE + (size_t)a * HW + pos0;
    float* op = out + row0 * NATT;
    const int nfl = valid * NATT;          // 5440 or 1360, both divisible by 4
    for (int i = tid * 4; i + 3 < nfl; i += 1024) {
        __builtin_nontemporal_store(*reinterpret_cast<const v4f*>(lds + i),
                                    reinterpret_cast<v4f*>(op + i));
    }
}

// Block counts: lvl2 = 100*3*32 = 9600, lvl1 = 25*3*32 = 2400,
// lvl0 = 7*3*32 = 672. Total 12672. Biggest level first.
__global__ __launch_bounds__(256) void yolox_fused(const float* __restrict__ in0,
                                                   const float* __restrict__ in1,
                                                   const float* __restrict__ in2,
                                                   float* __restrict__ out) {
    __shared__ float lds[TP * NATT];   // 21760 B, shared by all paths
    const int bid = blockIdx.x;
    if (bid < 9600) {
        process<2>(in2, out, bid, lds);
    } else if (bid < 12000) {
        process<1>(in1, out, bid - 9600, lds);
    } else {
        process<0>(in0, out, bid - 12000, lds);
    }
}

extern "C" void kernel_launch(void* const* d_in, const int* in_sizes, int n_in,
                              void* d_out, int out_size, void* d_ws, size_t ws_size,
                              hipStream_t stream) {
    const float* in0 = (const float*)d_in[0];  // (32,255,20,20)
    const float* in1 = (const float*)d_in[1];  // (32,255,40,40)
    const float* in2 = (const float*)d_in[2];  // (32,255,80,80)
    float* out = (float*)d_out;                // (32,25200,85)

    yolox_fused<<<dim3(12672), dim3(256), 0, stream>>>(in0, in1, in2, out);
}

// Round 5
// 91.402 us; speedup vs baseline: 1.3086x; 1.0461x over previous
//
#include <hip/hip_runtime.h>

// YOLOX head decode, fused single-launch, TP=64, MLP-staged loads.
// (N, A*85, H, W) -> (N, A*H*W, 85) with sigmoid on obj/cls and box decode
// on channels 0..3. Streaming transpose: coalesced float4 reads per
// channel-plane -> registers (all ~6 planes in flight per thread) ->
// sigmoid -> LDS [pos][85] -> coalesced float4 writes of the contiguous
// output region. Plain loads (allocate in 256 MiB Infinity Cache; inputs
// are re-read every graph replay), nontemporal stores (touch-once output,
// don't evict the inputs).

typedef float v4f __attribute__((ext_vector_type(4)));

#define NATT 85
#define TP 64              // positions per block
#define TOTAL_ROWS 25200
#define NIT 6              // ceil(85/16) plane-iterations per thread

__device__ __forceinline__ float sigmf(float v) {
    return 1.0f / (1.0f + __expf(-v));
}

template <int LVL>
__device__ __forceinline__ void process(const float* __restrict__ in,
                                        float* __restrict__ out,
                                        int id, float* lds) {
    constexpr int   H  = (LVL == 0) ? 20 : (LVL == 1) ? 40 : 80;
    constexpr int   W  = H;
    constexpr int   HW = H * W;
    constexpr float S  = (LVL == 0) ? 32.f : (LVL == 1) ? 16.f : 8.f;
    constexpr int   OUT_BASE = (LVL == 0) ? 0 : (LVL == 1) ? 1200 : 6000;
    constexpr int   C  = (HW + TP - 1) / TP;   // chunks per (n,a): 7 / 25 / 100

    const int tid   = threadIdx.x;     // 256 threads = 4 waves
    const int chunk = id % C;
    const int ta    = id / C;
    const int a     = ta % 3;          // anchor
    const int n     = ta / 3;          // batch

    const int pos0  = chunk * TP;
    const int valid = (HW - pos0 < TP) ? (HW - pos0) : TP;  // 64, or 16 (lvl0 tail)

    // input plane base for (n, anchor a, k=0) at this position chunk
    const float* inp = in + ((size_t)n * 255 + (size_t)a * NATT) * HW + pos0;

    // ---- load phase: stage all plane loads first (MLP=6), then scatter ----
    const int m  = tid & 15;       // which float4 within the 64-pos chunk
    const int p  = m * 4;          // position offset of this vec
    const int k0 = tid >> 4;       // first plane of this thread
    const bool act = (p < valid);  // valid is always a multiple of 4

    v4f r[NIT];
#pragma unroll
    for (int it = 0; it < NIT; ++it) {
        const int kk = k0 + it * 16;
        if (kk < NATT && act) {
            r[it] = *reinterpret_cast<const v4f*>(inp + (size_t)kk * HW + p);
        }
    }
#pragma unroll
    for (int it = 0; it < NIT; ++it) {
        const int kk = k0 + it * 16;
        if (kk < NATT && act) {
            v4f v = r[it];
            if (kk >= 4) {
                v.x = sigmf(v.x); v.y = sigmf(v.y);
                v.z = sigmf(v.z); v.w = sigmf(v.w);
            }
            lds[(p + 0) * NATT + kk] = v.x;
            lds[(p + 1) * NATT + kk] = v.y;
            lds[(p + 2) * NATT + kk] = v.z;
            lds[(p + 3) * NATT + kk] = v.w;
        }
    }
    __syncthreads();

    // ---- fix-up phase: decode boxes in place (one lane per position) ----
    if (tid < TP && tid < valid) {
        const int gp = pos0 + tid;
        const int y  = gp / W;
        const int x  = gp - y * W;
        const float wa = (a == 0) ? ((LVL == 0) ? 116.f : (LVL == 1) ? 30.f : 10.f)
                       : (a == 1) ? ((LVL == 0) ? 156.f : (LVL == 1) ? 62.f : 16.f)
                                  : ((LVL == 0) ? 373.f : (LVL == 1) ? 59.f : 33.f);
        const float ha = (a == 0) ? ((LVL == 0) ?  90.f : (LVL == 1) ? 61.f : 13.f)
                       : (a == 1) ? ((LVL == 0) ? 198.f : (LVL == 1) ? 45.f : 30.f)
                                  : ((LVL == 0) ? 326.f : (LVL == 1) ? 119.f : 23.f);
        const float p0 = lds[tid * NATT + 0];
        const float p1 = lds[tid * NATT + 1];
        const float p2 = lds[tid * NATT + 2];
        const float p3 = lds[tid * NATT + 3];
        // (p0-0.5)*S + (x+0.5)*S == (p0+x)*S
        const float xc = (p0 + (float)x) * S;
        const float yc = (p1 + (float)y) * S;
        const float w  = __expf(p2) * wa;
        const float h  = __expf(p3) * ha;
        lds[tid * NATT + 0] = xc - 0.5f * w;
        lds[tid * NATT + 1] = yc - 0.5f * h;
        lds[tid * NATT + 2] = xc + 0.5f * w;
        lds[tid * NATT + 3] = yc + 0.5f * h;
    }
    __syncthreads();

    // ---- write phase: output region is valid*85 contiguous floats ----
    const size_t row0 = (size_t)n * TOTAL_ROWS + OUT_BASE + (size_t)a * HW + pos0;
    float* op = out + row0 * NATT;
    const int nfl = valid * NATT;          // 5440 or 1360, both divisible by 4
    for (int i = tid * 4; i + 3 < nfl; i += 1024) {
        __builtin_nontemporal_store(*reinterpret_cast<const v4f*>(lds + i),
                                    reinterpret_cast<v4f*>(op + i));
    }
}

// Block counts: lvl2 = 100*3*32 = 9600, lvl1 = 25*3*32 = 2400,
// lvl0 = 7*3*32 = 672. Total 12672. Biggest level first.
__global__ __launch_bounds__(256) void yolox_fused(const float* __restrict__ in0,
                                                   const float* __restrict__ in1,
                                                   const float* __restrict__ in2,
                                                   float* __restrict__ out) {
    __shared__ float lds[TP * NATT];   // 21760 B, shared by all paths
    const int bid = blockIdx.x;
    if (bid < 9600) {
        process<2>(in2, out, bid, lds);
    } else if (bid < 12000) {
        process<1>(in1, out, bid - 9600, lds);
    } else {
        process<0>(in0, out, bid - 12000, lds);
    }
}

extern "C" void kernel_launch(void* const* d_in, const int* in_sizes, int n_in,
                              void* d_out, int out_size, void* d_ws, size_t ws_size,
                              hipStream_t stream) {
    const float* in0 = (const float*)d_in[0];  // (32,255,20,20)
    const float* in1 = (const float*)d_in[1];  // (32,255,40,40)
    const float* in2 = (const float*)d_in[2];  // (32,255,80,80)
    float* out = (float*)d_out;                // (32,25200,85)

    yolox_fused<<<dim3(12672), dim3(256), 0, stream>>>(in0, in1, in2, out);
}